// Round 16
// baseline (526.889 us; speedup 1.0000x reference)
//
#include <hip/hip_runtime.h>
#include <hip/hip_bf16.h>

typedef __bf16 bf16_t;
typedef bf16_t bf16x8 __attribute__((ext_vector_type(8)));
typedef float f32x4 __attribute__((ext_vector_type(4)));

#define EPSV 1e-5f

__global__ void k_zerof(float* p, int cnt) {
  int i = blockIdx.x * 256 + threadIdx.x;
  if (i < cnt) p[i] = 0.f;
}
__global__ void k_zeroi(int* p, int cnt) {
  int i = blockIdx.x * 256 + threadIdx.x;
  if (i < cnt) p[i] = 0;
}

// merged one-time prep: weights | film | te | ecomb
__global__ void k_prep_all(const float* __restrict__ W1, const float* __restrict__ W2,
                           bf16_t* __restrict__ W1T, bf16_t* __restrict__ W2T,
                           const float* __restrict__ Wg, const float* __restrict__ Wb,
                           bf16_t* __restrict__ fWT,
                           const float* __restrict__ te, bf16_t* __restrict__ teb,
                           const float* __restrict__ e1, const float* __restrict__ e2,
                           float* __restrict__ ec, int L, int g) {
  int idx = blockIdx.x * 256 + threadIdx.x;
  int base0 = L * 32768;
  int base1 = base0 + 4 * 16384;
  int base2 = base1 + g * 128;
  int base3 = base2 + L * 18 * 128;
  if (idx < base0) {
    int l = idx >> 15, r = idx & 32767;
    int k = r >> 8, c = r & 255;
    W1T[(l << 15) + c * 128 + k] = (bf16_t)W1[idx];
    int k2 = r >> 7, c2 = r & 127;
    W2T[(l << 15) + c2 * 256 + k2] = (bf16_t)W2[idx];
  } else if (idx < base1) {
    int i2 = idx - base0;
    int m = i2 >> 14, r = i2 & 16383;
    int c = r >> 7, k = r & 127;
    const float* W = ((m & 1) ? Wb : Wg) + (m >> 1) * 16384;
    fWT[i2] = (bf16_t)W[k * 128 + c];
  } else if (idx < base2) {
    int i2 = idx - base1;
    teb[i2] = (bf16_t)te[i2];
  } else if (idx < base3) {
    int i2 = idx - base2;
    int ch = i2 & 127;
    int t = i2 >> 7;
    int comb = t % 18, l = t / 18;
    int i = comb / 3, j = comb % 3;
    ec[i2] = e1[(l * 6 + i) * 128 + ch] + e2[(l * 3 + j) * 128 + ch];
  }
}

// FiLM GEMM via MFMA: gbuf[m][row][col] = te @ W[m] + b[m]; 4 waves, wave owns 32 cols.
__launch_bounds__(256, 2)
__global__ void k_film(const bf16_t* __restrict__ teb, const bf16_t* __restrict__ fWT,
                       const float* __restrict__ bg, const float* __restrict__ bb,
                       float* __restrict__ gbuf, int g) {
  const int mat = blockIdx.x & 3;
  const int r0 = (blockIdx.x >> 2) * 64;
  const int tid = threadIdx.x;
  const int wave = tid >> 6, lane = tid & 63;
  const int lr = lane & 15, lk = lane >> 4;
  const int w32 = wave * 32;
  const bf16_t* W = fWT + mat * 16384;
  const float* B = ((mat & 1) ? bb : bg) + (mat >> 1) * 128;

  bf16x8 bbf[2][4];
  #pragma unroll
  for (int cf = 0; cf < 2; ++cf)
    #pragma unroll
    for (int kk = 0; kk < 4; ++kk)
      bbf[cf][kk] = *(const bf16x8*)(W + ((w32 + cf * 16 + lr) << 7) + kk * 32 + (lk << 3));

  f32x4 acc[4][2];
  f32x4 zero4 = {0.f, 0.f, 0.f, 0.f};
  #pragma unroll
  for (int rf = 0; rf < 4; ++rf)
    #pragma unroll
    for (int cf = 0; cf < 2; ++cf) acc[rf][cf] = zero4;

  #pragma unroll
  for (int kk = 0; kk < 4; ++kk) {
    bf16x8 a[4];
    #pragma unroll
    for (int rf = 0; rf < 4; ++rf)
      a[rf] = *(const bf16x8*)(teb + ((size_t)(r0 + rf * 16 + lr) << 7) + kk * 32 + (lk << 3));
    #pragma unroll
    for (int rf = 0; rf < 4; ++rf)
      #pragma unroll
      for (int cf = 0; cf < 2; ++cf)
        acc[rf][cf] = __builtin_amdgcn_mfma_f32_16x16x32_bf16(a[rf], bbf[cf][kk], acc[rf][cf], 0, 0, 0);
  }

  float* out = gbuf + (size_t)mat * g * 128;
  #pragma unroll
  for (int cf = 0; cf < 2; ++cf) {
    int col = w32 + cf * 16 + lr;
    float bias = B[col];
    #pragma unroll
    for (int rf = 0; rf < 4; ++rf)
      #pragma unroll
      for (int j = 0; j < 4; ++j) {
        int row = r0 + rf * 16 + lk * 4 + j;
        out[(size_t)row * 128 + col] = acc[rf][cf][j] + bias;
      }
  }
}

__global__ void k_init_x(const int* __restrict__ xa, const float* __restrict__ teb,
                         const float* __restrict__ emb1, const float* __restrict__ emb2,
                         bf16_t* __restrict__ x, int n, int N) {
  int idx = blockIdx.x * 256 + threadIdx.x;
  if (idx >= N * 128) return;
  int row = idx >> 7, ch = idx & 127;
  float v;
  if (row < n) v = emb1[xa[row * 2] * 128 + ch] + emb2[xa[row * 2 + 1] * 128 + ch];
  else v = teb[(size_t)(row - n) * 128 + ch];
  x[idx] = (bf16_t)v;
}

__global__ void k_hist(const int* __restrict__ eidx, int* __restrict__ cnt, int E) {
  int i = blockIdx.x * 256 + threadIdx.x;
  if (i < E) atomicAdd(&cnt[eidx[E + i]], 1);
}

__global__ void k_scan1(const int* __restrict__ cnt, int* __restrict__ part,
                        int* __restrict__ bsum, int n) {
  __shared__ int s[256];
  int i = blockIdx.x * 256 + threadIdx.x;
  int v = (i < n) ? cnt[i] : 0;
  s[threadIdx.x] = v;
  for (int off = 1; off < 256; off <<= 1) {
    __syncthreads();
    int t = (threadIdx.x >= off) ? s[threadIdx.x - off] : 0;
    __syncthreads();
    s[threadIdx.x] += t;
  }
  __syncthreads();
  if (i < n) part[i] = s[threadIdx.x] - v;
  if (threadIdx.x == 255) bsum[blockIdx.x] = s[255];
}

__global__ void k_scan2(int* bsum, int nb) {
  __shared__ int s[512];
  int v = ((int)threadIdx.x < nb) ? bsum[threadIdx.x] : 0;
  s[threadIdx.x] = v;
  for (int off = 1; off < 512; off <<= 1) {
    __syncthreads();
    int t = ((int)threadIdx.x >= off) ? s[threadIdx.x - off] : 0;
    __syncthreads();
    s[threadIdx.x] += t;
  }
  __syncthreads();
  if ((int)threadIdx.x < nb) bsum[threadIdx.x] = s[threadIdx.x] - v;
}

__global__ void k_scan3(int* __restrict__ rp, const int* __restrict__ bsum,
                        int* __restrict__ fill, int n, int E) {
  int i = blockIdx.x * 256 + threadIdx.x;
  if (i < n) {
    int v = rp[i] + bsum[i >> 8];
    rp[i] = v;
    fill[i] = v;
  }
  if (i == 0) rp[n] = E;
}

__global__ void k_scatter(const int* __restrict__ eidx, const int* __restrict__ eattr,
                          int* __restrict__ fill, int* __restrict__ pack, int E) {
  int i = blockIdx.x * 256 + threadIdx.x;
  if (i >= E) return;
  int s = eidx[i];
  int d = eidx[E + i];
  int comb = eattr[2 * i] * 3 + eattr[2 * i + 1];
  int p = atomicAdd(&fill[d], 1);
  pack[p] = s | (comb << 20);
}

// normalize+relu pass with in-block batchnorm finalize; first 16 blocks zero the
// other gstats zone for the upcoming k_mlp.
__global__ void k_normx(const bf16_t* __restrict__ y, const float* __restrict__ part,
                        float* __restrict__ zother,
                        const float* __restrict__ bnw, const float* __restrict__ bnb,
                        float invN, bf16_t* __restrict__ xn, int total8) {
  __shared__ float ss[256];
  const int tid = threadIdx.x;
  if (tid < 128) {
    float s = 0.f, q = 0.f;
    #pragma unroll
    for (int c = 0; c < 16; ++c) { s += part[c * 256 + tid]; q += part[c * 256 + 128 + tid]; }
    float mean = s * invN;
    float var = fmaxf(q * invN - mean * mean, 0.f);
    float inv = rsqrtf(var + EPSV);
    float sc = inv * bnw[tid];
    ss[tid] = sc;
    ss[128 + tid] = bnb[tid] - mean * sc;
  }
  if (blockIdx.x < 16) zother[blockIdx.x * 256 + tid] = 0.f;
  __syncthreads();
  int i = blockIdx.x * 256 + tid;
  if (i >= total8) return;
  int ch0 = (i & 15) * 8;
  bf16x8 v = ((const bf16x8*)y)[i];
  bf16x8 o;
  #pragma unroll
  for (int j = 0; j < 8; ++j)
    o[j] = (bf16_t)fmaxf(fmaf((float)v[j], ss[ch0 + j], ss[128 + ch0 + j]), 0.f);
  ((bf16x8*)xn)[i] = o;
}

// agg = segment_sum(xn[src]+emb, dst) + xn + self_emb (xn already normalized).
// 16 lanes per node; ONE pack load + shfl broadcast per <=16-edge chunk;
// edges processed in batches of 4 with all loads issued before accumulation.
__global__ void k_agg(const bf16_t* __restrict__ xn, const int* __restrict__ batch,
                      const int* __restrict__ rp, const int* __restrict__ pack,
                      const float* __restrict__ ec,
                      bf16_t* __restrict__ agg, int n, int N, int npg) {
  int node = blockIdx.x * 16 + (threadIdx.x >> 4);
  if (node >= N) return;
  const int lane = threadIdx.x & 63;
  const int li = lane & 15;
  const int grpl = lane & 48;
  const int ch0 = li * 8;

  float4 s0 = *(const float4*)(ec + 12 * 128 + ch0);
  float4 s1 = *(const float4*)(ec + 12 * 128 + ch0 + 4);
  float4 v0 = *(const float4*)(ec + 15 * 128 + ch0);
  float4 v1 = *(const float4*)(ec + 15 * 128 + ch0 + 4);
  bf16x8 hs = *(const bf16x8*)(xn + ((size_t)node << 7) + ch0);
  float acc[8];

  if (node < n) {
    int b = batch[node];
    bf16x8 hv = *(const bf16x8*)(xn + ((size_t)(n + b) << 7) + ch0);
    acc[0] = (float)hs[0] + (float)hv[0] + s0.x + v0.x;
    acc[1] = (float)hs[1] + (float)hv[1] + s0.y + v0.y;
    acc[2] = (float)hs[2] + (float)hv[2] + s0.z + v0.z;
    acc[3] = (float)hs[3] + (float)hv[3] + s0.w + v0.w;
    acc[4] = (float)hs[4] + (float)hv[4] + s1.x + v1.x;
    acc[5] = (float)hs[5] + (float)hv[5] + s1.y + v1.y;
    acc[6] = (float)hs[6] + (float)hv[6] + s1.z + v1.z;
    acc[7] = (float)hs[7] + (float)hv[7] + s1.w + v1.w;
    int beg = rp[node], end = rp[node + 1];
    for (int base = beg; base < end; base += 16) {
      int cnt = end - base; if (cnt > 16) cnt = 16;
      int pl = pack[base + (li < cnt ? li : cnt - 1)];
      for (int j0 = 0; j0 < cnt; j0 += 4) {
        bf16x8 hx[4]; float4 e0[4], e1[4]; float m[4];
        #pragma unroll
        for (int u = 0; u < 4; ++u) {
          int j = j0 + u;
          int jj = j < cnt ? j : cnt - 1;
          m[u] = (j < cnt) ? 1.f : 0.f;
          int p = __shfl(pl, grpl | jj, 64);
          hx[u] = *(const bf16x8*)(xn + ((size_t)(p & 0xFFFFF) << 7) + ch0);
          const float* er = ec + ((p >> 20) & 31) * 128 + ch0;
          e0[u] = *(const float4*)er;
          e1[u] = *(const float4*)(er + 4);
        }
        #pragma unroll
        for (int u = 0; u < 4; ++u) {
          acc[0] = fmaf(m[u], (float)hx[u][0] + e0[u].x, acc[0]);
          acc[1] = fmaf(m[u], (float)hx[u][1] + e0[u].y, acc[1]);
          acc[2] = fmaf(m[u], (float)hx[u][2] + e0[u].z, acc[2]);
          acc[3] = fmaf(m[u], (float)hx[u][3] + e0[u].w, acc[3]);
          acc[4] = fmaf(m[u], (float)hx[u][4] + e1[u].x, acc[4]);
          acc[5] = fmaf(m[u], (float)hx[u][5] + e1[u].y, acc[5]);
          acc[6] = fmaf(m[u], (float)hx[u][6] + e1[u].z, acc[6]);
          acc[7] = fmaf(m[u], (float)hx[u][7] + e1[u].w, acc[7]);
        }
      }
    }
  } else {
    float fn = (float)npg;
    acc[0] = (float)hs[0] + s0.x + fn * v0.x;
    acc[1] = (float)hs[1] + s0.y + fn * v0.y;
    acc[2] = (float)hs[2] + s0.z + fn * v0.z;
    acc[3] = (float)hs[3] + s0.w + fn * v0.w;
    acc[4] = (float)hs[4] + s1.x + fn * v1.x;
    acc[5] = (float)hs[5] + s1.y + fn * v1.y;
    acc[6] = (float)hs[6] + s1.z + fn * v1.z;
    acc[7] = (float)hs[7] + s1.w + fn * v1.w;
    int base = (node - n) * npg;
    for (int k = 0; k < npg; k += 4) {
      bf16x8 hx[4];
      #pragma unroll
      for (int u = 0; u < 4; ++u)
        hx[u] = *(const bf16x8*)(xn + ((size_t)(base + k + u) << 7) + ch0);
      #pragma unroll
      for (int u = 0; u < 4; ++u)
        #pragma unroll
        for (int j = 0; j < 8; ++j) acc[j] += (float)hx[u][j];
    }
  }

  bf16x8 o;
  #pragma unroll
  for (int j = 0; j < 8; ++j) o[j] = (bf16_t)acc[j];
  *(bf16x8*)(agg + ((size_t)node << 7) + ch0) = o;
}

// Fused MLP (r11 skeleton): y = relu(agg@W1+b1)@W2+b2, FiLM, batchnorm stats.
// A-tile staged via async global_load_lds (width 16): LDS dest linear in slot
// order, inverse swizzle applied to per-lane global SOURCE address (rule #21),
// reproducing the previous swizzled layout bit-for-bit.
__launch_bounds__(512, 4)
__global__ void k_mlp(const bf16_t* __restrict__ agg, const bf16_t* __restrict__ W1T,
                      const bf16_t* __restrict__ W2T, const float* __restrict__ b1,
                      const float* __restrict__ b2, const float* __restrict__ gamma,
                      const float* __restrict__ beta, const int* __restrict__ batch,
                      bf16_t* __restrict__ y, float* __restrict__ gstats, int n, int N) {
  __shared__ __align__(16) char As[16384];   // [64][128] bf16, swizzled ^((r&7)<<4)
  __shared__ __align__(16) char Hs[32768];   // [64][256] bf16, swizzled ^((r&15)<<4)
  __shared__ float sred[256];
  const int tid = threadIdx.x;
  const int m0 = blockIdx.x * 64;
  const int wave = tid >> 6, lane = tid & 63;
  const int lr = lane & 15, lk = lane >> 4;
  if (tid < 256) sred[tid] = 0.f;

  // stage A tile async: slot s = it*512 + tid holds source column (s&15)^((s>>4)&7)
  // of row s>>4; HW writes LDS at wavebase + lane*16 (N % 64 == 0 -> no OOB).
  #pragma unroll
  for (int it = 0; it < 2; ++it) {
    int s = it * 512 + tid;
    int row = s >> 4;
    int c16 = (s & 15) ^ (row & 7);
    const bf16_t* src = agg + ((size_t)(m0 + row) << 7) + c16 * 8;
    char* ldsbase = As + (it * 8 + wave) * 1024;  // wave-uniform
    __builtin_amdgcn_global_load_lds(
        (const __attribute__((address_space(1))) void*)(const void*)src,
        (__attribute__((address_space(3))) void*)(void*)ldsbase, 16, 0, 0);
  }

  // preload GEMM1 B frags: wave owns cols [32*wave, 32*wave+32)
  const int c1base = wave * 32;
  bf16x8 bb1[2][4];
  #pragma unroll
  for (int cf = 0; cf < 2; ++cf)
    #pragma unroll
    for (int kk = 0; kk < 4; ++kk)
      bb1[cf][kk] = *(const bf16x8*)(W1T + ((c1base + cf * 16 + lr) << 7) + kk * 32 + (lk << 3));

  __syncthreads();   // drains vmcnt -> As fully staged

  f32x4 zero4 = {0.f, 0.f, 0.f, 0.f};
  f32x4 acc1[4][2];
  #pragma unroll
  for (int rf = 0; rf < 4; ++rf)
    #pragma unroll
    for (int cf = 0; cf < 2; ++cf) acc1[rf][cf] = zero4;

  #pragma unroll
  for (int kk = 0; kk < 4; ++kk) {
    bf16x8 a[4];
    #pragma unroll
    for (int rf = 0; rf < 4; ++rf) {
      int arow = rf * 16 + lr;
      int abyte = (arow << 8) + kk * 64 + (lk << 4);
      abyte ^= (arow & 7) << 4;
      a[rf] = *(const bf16x8*)(As + abyte);
    }
    #pragma unroll
    for (int rf = 0; rf < 4; ++rf)
      #pragma unroll
      for (int cf = 0; cf < 2; ++cf)
        acc1[rf][cf] = __builtin_amdgcn_mfma_f32_16x16x32_bf16(a[rf], bb1[cf][kk], acc1[rf][cf], 0, 0, 0);
  }

  // epilogue1: bias + relu -> Hs (bf16, swizzled)
  #pragma unroll
  for (int cf = 0; cf < 2; ++cf) {
    int col = c1base + cf * 16 + lr;
    float bias = b1[col];
    #pragma unroll
    for (int rf = 0; rf < 4; ++rf)
      #pragma unroll
      for (int j = 0; j < 4; ++j) {
        int r = rf * 16 + lk * 4 + j;
        float h = acc1[rf][cf][j] + bias;
        h = h > 0.f ? h : 0.f;
        int byte = (r << 9) + col * 2;
        byte ^= (r & 15) << 4;
        *(bf16_t*)(Hs + byte) = (bf16_t)h;
      }
  }

  // preload GEMM2 B frags: wave owns cols [16*wave, 16*wave+16)
  const int c2base = wave * 16;
  bf16x8 bb2[8];
  #pragma unroll
  for (int kk = 0; kk < 8; ++kk)
    bb2[kk] = *(const bf16x8*)(W2T + ((c2base + lr) << 8) + kk * 32 + (lk << 3));

  __syncthreads();

  f32x4 acc2[4];
  #pragma unroll
  for (int rf = 0; rf < 4; ++rf) acc2[rf] = zero4;

  #pragma unroll
  for (int kk = 0; kk < 8; ++kk) {
    bf16x8 a2[4];
    #pragma unroll
    for (int rf = 0; rf < 4; ++rf) {
      int row = rf * 16 + lr;
      int byte = (row << 9) + kk * 64 + (lk << 4);
      byte ^= (row & 15) << 4;
      a2[rf] = *(const bf16x8*)(Hs + byte);
    }
    #pragma unroll
    for (int rf = 0; rf < 4; ++rf)
      acc2[rf] = __builtin_amdgcn_mfma_f32_16x16x32_bf16(a2[rf], bb2[kk], acc2[rf], 0, 0, 0);
  }

  int gb[4][4];
  #pragma unroll
  for (int rf = 0; rf < 4; ++rf)
    #pragma unroll
    for (int j = 0; j < 4; ++j) {
      int row = m0 + rf * 16 + lk * 4 + j;
      gb[rf][j] = (gamma != nullptr && row < n) ? batch[row] : -1;
    }

  {
    int col = c2base + lr;
    float bias = b2[col];
    float s = 0.f, q = 0.f;
    #pragma unroll
    for (int rf = 0; rf < 4; ++rf)
      #pragma unroll
      for (int j = 0; j < 4; ++j) {
        int row = m0 + rf * 16 + lk * 4 + j;
        float v = acc2[rf][j] + bias;
        if (gb[rf][j] >= 0)
          v = gamma[(size_t)gb[rf][j] * 128 + col] * v + beta[(size_t)gb[rf][j] * 128 + col];
        y[(size_t)row * 128 + col] = (bf16_t)v;
        s += v; q += v * v;
      }
    s += __shfl_xor(s, 16, 64); s += __shfl_xor(s, 32, 64);
    q += __shfl_xor(q, 16, 64); q += __shfl_xor(q, 32, 64);
    if (lane < 16) { sred[col] = s; sred[128 + col] = q; }  // cols wave-partitioned
  }
  __syncthreads();
  if (tid < 256) atomicAdd(&gstats[((blockIdx.x & 15) << 8) + tid], sred[tid]);
}

// final normalize (no relu) with in-block finalize; first n rows -> d_out (f32)
__global__ void k_norm(const bf16_t* __restrict__ yin, const float* __restrict__ part,
                       const float* __restrict__ bnw, const float* __restrict__ bnb,
                       float invN, float* __restrict__ out, int total8) {
  __shared__ float ss[256];
  const int tid = threadIdx.x;
  if (tid < 128) {
    float s = 0.f, q = 0.f;
    #pragma unroll
    for (int c = 0; c < 16; ++c) { s += part[c * 256 + tid]; q += part[c * 256 + 128 + tid]; }
    float mean = s * invN;
    float var = fmaxf(q * invN - mean * mean, 0.f);
    float inv = rsqrtf(var + EPSV);
    float sc = inv * bnw[tid];
    ss[tid] = sc;
    ss[128 + tid] = bnb[tid] - mean * sc;
  }
  __syncthreads();
  int i = blockIdx.x * 256 + tid;
  if (i >= total8) return;
  int ch0 = (i & 15) * 8;
  bf16x8 v = ((const bf16x8*)yin)[i];
  float4 r0, r1;
  r0.x = (float)v[0] * ss[ch0 + 0] + ss[128 + ch0 + 0];
  r0.y = (float)v[1] * ss[ch0 + 1] + ss[128 + ch0 + 1];
  r0.z = (float)v[2] * ss[ch0 + 2] + ss[128 + ch0 + 2];
  r0.w = (float)v[3] * ss[ch0 + 3] + ss[128 + ch0 + 3];
  r1.x = (float)v[4] * ss[ch0 + 4] + ss[128 + ch0 + 4];
  r1.y = (float)v[5] * ss[ch0 + 5] + ss[128 + ch0 + 5];
  r1.z = (float)v[6] * ss[ch0 + 6] + ss[128 + ch0 + 6];
  r1.w = (float)v[7] * ss[ch0 + 7] + ss[128 + ch0 + 7];
  ((float4*)out)[i * 2] = r0;
  ((float4*)out)[i * 2 + 1] = r1;
}

extern "C" void kernel_launch(void* const* d_in, const int* in_sizes, int n_in,
                              void* d_out, int out_size, void* d_ws, size_t ws_size,
                              hipStream_t stream) {
  const int*   x_atoms    = (const int*)d_in[0];
  const int*   edge_index = (const int*)d_in[1];
  const int*   edge_attr  = (const int*)d_in[2];
  const int*   batch      = (const int*)d_in[3];
  const float* task_embs  = (const float*)d_in[6];
  const float* teb        = (const float*)d_in[7];
  const float* emb1       = (const float*)d_in[8];
  const float* emb2       = (const float*)d_in[9];
  const float* edge_e1    = (const float*)d_in[10];
  const float* edge_e2    = (const float*)d_in[11];
  const float* W1         = (const float*)d_in[12];
  const float* b1         = (const float*)d_in[13];
  const float* W2         = (const float*)d_in[14];
  const float* b2         = (const float*)d_in[15];
  const float* bnw        = (const float*)d_in[16];
  const float* bnb        = (const float*)d_in[17];
  const float* fWg        = (const float*)d_in[18];
  const float* fbg        = (const float*)d_in[19];
  const float* fWb        = (const float*)d_in[20];
  const float* fbb        = (const float*)d_in[21];

  const int n   = in_sizes[0] / 2;
  const int E   = in_sizes[1] / 2;
  const int g   = in_sizes[6] / 128;
  const int N   = n + g;
  const int npg = n / g;
  const int L   = in_sizes[12] / 32768;

  char* ws = (char*)d_ws;
  size_t off = 0;
  auto alloc = [&](size_t bytes) { size_t o = off; off += (bytes + 255) & ~(size_t)255; return o; };
  bf16_t* xbuf   = (bf16_t*)(ws + alloc((size_t)N * 128 * 2));
  bf16_t* xn     = (bf16_t*)(ws + alloc((size_t)N * 128 * 2));
  bf16_t* aggb   = (bf16_t*)(ws + alloc((size_t)N * 128 * 2));
  float*  gbuf   = (float*)(ws + alloc((size_t)4 * g * 128 * 4));
  bf16_t* W1Tb   = (bf16_t*)(ws + alloc((size_t)L * 32768 * 2));
  bf16_t* W2Tb   = (bf16_t*)(ws + alloc((size_t)L * 32768 * 2));
  bf16_t* fWTb   = (bf16_t*)(ws + alloc((size_t)4 * 16384 * 2));
  bf16_t* tebuf  = (bf16_t*)(ws + alloc((size_t)g * 128 * 2));
  float*  ecomb  = (float*)(ws + alloc((size_t)L * 18 * 128 * 4));
  float*  gstats = (float*)(ws + alloc((size_t)8192 * 4));   // 2 ping-pong zones x 4096
  int*    row_ptr= (int*)(ws + alloc((size_t)(n + 1) * 4));
  int*    fill   = (int*)(ws + alloc((size_t)n * 4));
  int*    epack  = (int*)(ws + alloc((size_t)E * 4));
  int*    bsum   = (int*)(ws + alloc(512 * 4));
  (void)ws_size; (void)n_in; (void)out_size;

  // one-time-per-launch precompute (merged)
  const int prep_total = L * 32768 + 4 * 16384 + g * 128 + L * 18 * 128;
  k_prep_all<<<(prep_total + 255) / 256, 256, 0, stream>>>(W1, W2, W1Tb, W2Tb,
      fWg, fWb, fWTb, task_embs, tebuf, edge_e1, edge_e2, ecomb, L, g);
  k_init_x<<<(N * 128 + 255) / 256, 256, 0, stream>>>(x_atoms, teb, emb1, emb2, xn, n, N);
  k_film<<<(g / 64) * 4, 256, 0, stream>>>(tebuf, fWTb, fbg, fbb, gbuf, g);

  // CSR build (by dst) for real edges
  const int nb = (n + 255) / 256;
  k_zeroi<<<nb, 256, 0, stream>>>(fill, n);
  k_hist<<<(E + 255) / 256, 256, 0, stream>>>(edge_index, fill, E);
  k_scan1<<<nb, 256, 0, stream>>>(fill, row_ptr, bsum, n);
  k_scan2<<<1, 512, 0, stream>>>(bsum, nb);
  k_scan3<<<nb, 256, 0, stream>>>(row_ptr, bsum, fill, n, E);
  k_scatter<<<(E + 255) / 256, 256, 0, stream>>>(edge_index, edge_attr, fill, epack, E);

  k_zerof<<<32, 256, 0, stream>>>(gstats, 8192);   // zero both zones once
  const float invN = 1.0f / (float)N;
  for (int l = 0; l < 4; ++l) {
    float* zone  = gstats + (size_t)(l & 1) * 4096;          // mlp(l) atomics target
    float* zprev = gstats + (size_t)((l - 1) & 1) * 4096;    // stats of layer l-1
    if (l > 0)
      k_normx<<<(N * 16 + 255) / 256, 256, 0, stream>>>(xbuf, zprev, zone,
          bnw + (l - 1) * 128, bnb + (l - 1) * 128, invN, xn, N * 16);
    k_agg<<<(N + 15) / 16, 256, 0, stream>>>(xn, batch, row_ptr, epack,
        ecomb + (size_t)l * 18 * 128, aggb, n, N, npg);
    const float* gm = nullptr; const float* bt = nullptr;
    if (l == 1) { gm = gbuf;                       bt = gbuf + (size_t)g * 128; }
    if (l == 3) { gm = gbuf + (size_t)2 * g * 128; bt = gbuf + (size_t)3 * g * 128; }
    k_mlp<<<(N + 63) / 64, 512, 0, stream>>>(aggb, W1Tb + (size_t)l * 32768,
        W2Tb + (size_t)l * 32768, b1 + l * 256, b2 + l * 128, gm, bt, batch,
        xbuf, zone, n, N);
  }
  // layer 3 stats live in zone 1
  k_norm<<<(n * 16 + 255) / 256, 256, 0, stream>>>(xbuf, gstats + 4096,
      bnw + 3 * 128, bnb + 3 * 128, invN, (float*)d_out, n * 16);
}

// Round 17
// 520.550 us; speedup vs baseline: 1.0122x; 1.0122x over previous
//
#include <hip/hip_runtime.h>
#include <hip/hip_bf16.h>

typedef __bf16 bf16_t;
typedef bf16_t bf16x8 __attribute__((ext_vector_type(8)));
typedef float f32x4 __attribute__((ext_vector_type(4)));

#define EPSV 1e-5f

__global__ void k_zerof(float* p, int cnt) {
  int i = blockIdx.x * 256 + threadIdx.x;
  if (i < cnt) p[i] = 0.f;
}
__global__ void k_zeroi(int* p, int cnt) {
  int i = blockIdx.x * 256 + threadIdx.x;
  if (i < cnt) p[i] = 0;
}

// merged one-time prep: weights | film | te | ecomb
__global__ void k_prep_all(const float* __restrict__ W1, const float* __restrict__ W2,
                           bf16_t* __restrict__ W1T, bf16_t* __restrict__ W2T,
                           const float* __restrict__ Wg, const float* __restrict__ Wb,
                           bf16_t* __restrict__ fWT,
                           const float* __restrict__ te, bf16_t* __restrict__ teb,
                           const float* __restrict__ e1, const float* __restrict__ e2,
                           float* __restrict__ ec, int L, int g) {
  int idx = blockIdx.x * 256 + threadIdx.x;
  int base0 = L * 32768;
  int base1 = base0 + 4 * 16384;
  int base2 = base1 + g * 128;
  int base3 = base2 + L * 18 * 128;
  if (idx < base0) {
    int l = idx >> 15, r = idx & 32767;
    int k = r >> 8, c = r & 255;
    W1T[(l << 15) + c * 128 + k] = (bf16_t)W1[idx];
    int k2 = r >> 7, c2 = r & 127;
    W2T[(l << 15) + c2 * 256 + k2] = (bf16_t)W2[idx];
  } else if (idx < base1) {
    int i2 = idx - base0;
    int m = i2 >> 14, r = i2 & 16383;
    int c = r >> 7, k = r & 127;
    const float* W = ((m & 1) ? Wb : Wg) + (m >> 1) * 16384;
    fWT[i2] = (bf16_t)W[k * 128 + c];
  } else if (idx < base2) {
    int i2 = idx - base1;
    teb[i2] = (bf16_t)te[i2];
  } else if (idx < base3) {
    int i2 = idx - base2;
    int ch = i2 & 127;
    int t = i2 >> 7;
    int comb = t % 18, l = t / 18;
    int i = comb / 3, j = comb % 3;
    ec[i2] = e1[(l * 6 + i) * 128 + ch] + e2[(l * 3 + j) * 128 + ch];
  }
}

// FiLM GEMM via MFMA: gbuf[m][row][col] = te @ W[m] + b[m]; 4 waves, wave owns 32 cols.
__launch_bounds__(256, 2)
__global__ void k_film(const bf16_t* __restrict__ teb, const bf16_t* __restrict__ fWT,
                       const float* __restrict__ bg, const float* __restrict__ bb,
                       float* __restrict__ gbuf, int g) {
  const int mat = blockIdx.x & 3;
  const int r0 = (blockIdx.x >> 2) * 64;
  const int tid = threadIdx.x;
  const int wave = tid >> 6, lane = tid & 63;
  const int lr = lane & 15, lk = lane >> 4;
  const int w32 = wave * 32;
  const bf16_t* W = fWT + mat * 16384;
  const float* B = ((mat & 1) ? bb : bg) + (mat >> 1) * 128;

  bf16x8 bbf[2][4];
  #pragma unroll
  for (int cf = 0; cf < 2; ++cf)
    #pragma unroll
    for (int kk = 0; kk < 4; ++kk)
      bbf[cf][kk] = *(const bf16x8*)(W + ((w32 + cf * 16 + lr) << 7) + kk * 32 + (lk << 3));

  f32x4 acc[4][2];
  f32x4 zero4 = {0.f, 0.f, 0.f, 0.f};
  #pragma unroll
  for (int rf = 0; rf < 4; ++rf)
    #pragma unroll
    for (int cf = 0; cf < 2; ++cf) acc[rf][cf] = zero4;

  #pragma unroll
  for (int kk = 0; kk < 4; ++kk) {
    bf16x8 a[4];
    #pragma unroll
    for (int rf = 0; rf < 4; ++rf)
      a[rf] = *(const bf16x8*)(teb + ((size_t)(r0 + rf * 16 + lr) << 7) + kk * 32 + (lk << 3));
    #pragma unroll
    for (int rf = 0; rf < 4; ++rf)
      #pragma unroll
      for (int cf = 0; cf < 2; ++cf)
        acc[rf][cf] = __builtin_amdgcn_mfma_f32_16x16x32_bf16(a[rf], bbf[cf][kk], acc[rf][cf], 0, 0, 0);
  }

  float* out = gbuf + (size_t)mat * g * 128;
  #pragma unroll
  for (int cf = 0; cf < 2; ++cf) {
    int col = w32 + cf * 16 + lr;
    float bias = B[col];
    #pragma unroll
    for (int rf = 0; rf < 4; ++rf)
      #pragma unroll
      for (int j = 0; j < 4; ++j) {
        int row = r0 + rf * 16 + lk * 4 + j;
        out[(size_t)row * 128 + col] = acc[rf][cf][j] + bias;
      }
  }
}

__global__ void k_init_x(const int* __restrict__ xa, const float* __restrict__ teb,
                         const float* __restrict__ emb1, const float* __restrict__ emb2,
                         bf16_t* __restrict__ x, int n, int N) {
  int idx = blockIdx.x * 256 + threadIdx.x;
  if (idx >= N * 128) return;
  int row = idx >> 7, ch = idx & 127;
  float v;
  if (row < n) v = emb1[xa[row * 2] * 128 + ch] + emb2[xa[row * 2 + 1] * 128 + ch];
  else v = teb[(size_t)(row - n) * 128 + ch];
  x[idx] = (bf16_t)v;
}

__global__ void k_hist(const int* __restrict__ eidx, int* __restrict__ cnt, int E) {
  int i = blockIdx.x * 256 + threadIdx.x;
  if (i < E) atomicAdd(&cnt[eidx[E + i]], 1);
}

__global__ void k_scan1(const int* __restrict__ cnt, int* __restrict__ part,
                        int* __restrict__ bsum, int n) {
  __shared__ int s[256];
  int i = blockIdx.x * 256 + threadIdx.x;
  int v = (i < n) ? cnt[i] : 0;
  s[threadIdx.x] = v;
  for (int off = 1; off < 256; off <<= 1) {
    __syncthreads();
    int t = (threadIdx.x >= off) ? s[threadIdx.x - off] : 0;
    __syncthreads();
    s[threadIdx.x] += t;
  }
  __syncthreads();
  if (i < n) part[i] = s[threadIdx.x] - v;
  if (threadIdx.x == 255) bsum[blockIdx.x] = s[255];
}

__global__ void k_scan2(int* bsum, int nb) {
  __shared__ int s[512];
  int v = ((int)threadIdx.x < nb) ? bsum[threadIdx.x] : 0;
  s[threadIdx.x] = v;
  for (int off = 1; off < 512; off <<= 1) {
    __syncthreads();
    int t = ((int)threadIdx.x >= off) ? s[threadIdx.x - off] : 0;
    __syncthreads();
    s[threadIdx.x] += t;
  }
  __syncthreads();
  if ((int)threadIdx.x < nb) bsum[threadIdx.x] = s[threadIdx.x] - v;
}

__global__ void k_scan3(int* __restrict__ rp, const int* __restrict__ bsum,
                        int* __restrict__ fill, int n, int E) {
  int i = blockIdx.x * 256 + threadIdx.x;
  if (i < n) {
    int v = rp[i] + bsum[i >> 8];
    rp[i] = v;
    fill[i] = v;
  }
  if (i == 0) rp[n] = E;
}

__global__ void k_scatter(const int* __restrict__ eidx, const int* __restrict__ eattr,
                          int* __restrict__ fill, int* __restrict__ pack, int E) {
  int i = blockIdx.x * 256 + threadIdx.x;
  if (i >= E) return;
  int s = eidx[i];
  int d = eidx[E + i];
  int comb = eattr[2 * i] * 3 + eattr[2 * i + 1];
  int p = atomicAdd(&fill[d], 1);
  pack[p] = s | (comb << 20);
}

// normalize+relu pass with in-block batchnorm finalize: every block reduces the
// 16 partial copies into sc/sh in LDS; first 16 blocks zero the OTHER gstats zone.
__global__ void k_normx(const bf16_t* __restrict__ y, const float* __restrict__ part,
                        float* __restrict__ zother,
                        const float* __restrict__ bnw, const float* __restrict__ bnb,
                        float invN, bf16_t* __restrict__ xn, int total8) {
  __shared__ float ss[256];
  const int tid = threadIdx.x;
  if (tid < 128) {
    float s = 0.f, q = 0.f;
    #pragma unroll
    for (int c = 0; c < 16; ++c) { s += part[c * 256 + tid]; q += part[c * 256 + 128 + tid]; }
    float mean = s * invN;
    float var = fmaxf(q * invN - mean * mean, 0.f);
    float inv = rsqrtf(var + EPSV);
    float sc = inv * bnw[tid];
    ss[tid] = sc;
    ss[128 + tid] = bnb[tid] - mean * sc;
  }
  if (blockIdx.x < 16) zother[blockIdx.x * 256 + tid] = 0.f;
  __syncthreads();
  int i = blockIdx.x * 256 + tid;
  if (i >= total8) return;
  int ch0 = (i & 15) * 8;
  bf16x8 v = ((const bf16x8*)y)[i];
  bf16x8 o;
  #pragma unroll
  for (int j = 0; j < 8; ++j)
    o[j] = (bf16_t)fmaxf(fmaf((float)v[j], ss[ch0 + j], ss[128 + ch0 + j]), 0.f);
  ((bf16x8*)xn)[i] = o;
}

// agg = segment_sum(xn[src]+emb, dst) + xn + self_emb (xn already normalized).
// 16 lanes per node; ONE pack load + shfl broadcast per <=16-edge chunk;
// edges processed in batches of 4 with all loads issued before accumulation.
__global__ void k_agg(const bf16_t* __restrict__ xn, const int* __restrict__ batch,
                      const int* __restrict__ rp, const int* __restrict__ pack,
                      const float* __restrict__ ec,
                      bf16_t* __restrict__ agg, int n, int N, int npg) {
  int node = blockIdx.x * 16 + (threadIdx.x >> 4);
  if (node >= N) return;
  const int lane = threadIdx.x & 63;
  const int li = lane & 15;
  const int grpl = lane & 48;
  const int ch0 = li * 8;

  float4 s0 = *(const float4*)(ec + 12 * 128 + ch0);
  float4 s1 = *(const float4*)(ec + 12 * 128 + ch0 + 4);
  float4 v0 = *(const float4*)(ec + 15 * 128 + ch0);
  float4 v1 = *(const float4*)(ec + 15 * 128 + ch0 + 4);
  bf16x8 hs = *(const bf16x8*)(xn + ((size_t)node << 7) + ch0);
  float acc[8];

  if (node < n) {
    int b = batch[node];
    bf16x8 hv = *(const bf16x8*)(xn + ((size_t)(n + b) << 7) + ch0);
    acc[0] = (float)hs[0] + (float)hv[0] + s0.x + v0.x;
    acc[1] = (float)hs[1] + (float)hv[1] + s0.y + v0.y;
    acc[2] = (float)hs[2] + (float)hv[2] + s0.z + v0.z;
    acc[3] = (float)hs[3] + (float)hv[3] + s0.w + v0.w;
    acc[4] = (float)hs[4] + (float)hv[4] + s1.x + v1.x;
    acc[5] = (float)hs[5] + (float)hv[5] + s1.y + v1.y;
    acc[6] = (float)hs[6] + (float)hv[6] + s1.z + v1.z;
    acc[7] = (float)hs[7] + (float)hv[7] + s1.w + v1.w;
    int beg = rp[node], end = rp[node + 1];
    for (int base = beg; base < end; base += 16) {
      int cnt = end - base; if (cnt > 16) cnt = 16;
      int pl = pack[base + (li < cnt ? li : cnt - 1)];
      for (int j0 = 0; j0 < cnt; j0 += 4) {
        bf16x8 hx[4]; float4 e0[4], e1[4]; float m[4];
        #pragma unroll
        for (int u = 0; u < 4; ++u) {
          int j = j0 + u;
          int jj = j < cnt ? j : cnt - 1;
          m[u] = (j < cnt) ? 1.f : 0.f;
          int p = __shfl(pl, grpl | jj, 64);
          hx[u] = *(const bf16x8*)(xn + ((size_t)(p & 0xFFFFF) << 7) + ch0);
          const float* er = ec + ((p >> 20) & 31) * 128 + ch0;
          e0[u] = *(const float4*)er;
          e1[u] = *(const float4*)(er + 4);
        }
        #pragma unroll
        for (int u = 0; u < 4; ++u) {
          acc[0] = fmaf(m[u], (float)hx[u][0] + e0[u].x, acc[0]);
          acc[1] = fmaf(m[u], (float)hx[u][1] + e0[u].y, acc[1]);
          acc[2] = fmaf(m[u], (float)hx[u][2] + e0[u].z, acc[2]);
          acc[3] = fmaf(m[u], (float)hx[u][3] + e0[u].w, acc[3]);
          acc[4] = fmaf(m[u], (float)hx[u][4] + e1[u].x, acc[4]);
          acc[5] = fmaf(m[u], (float)hx[u][5] + e1[u].y, acc[5]);
          acc[6] = fmaf(m[u], (float)hx[u][6] + e1[u].z, acc[6]);
          acc[7] = fmaf(m[u], (float)hx[u][7] + e1[u].w, acc[7]);
        }
      }
    }
  } else {
    float fn = (float)npg;
    acc[0] = (float)hs[0] + s0.x + fn * v0.x;
    acc[1] = (float)hs[1] + s0.y + fn * v0.y;
    acc[2] = (float)hs[2] + s0.z + fn * v0.z;
    acc[3] = (float)hs[3] + s0.w + fn * v0.w;
    acc[4] = (float)hs[4] + s1.x + fn * v1.x;
    acc[5] = (float)hs[5] + s1.y + fn * v1.y;
    acc[6] = (float)hs[6] + s1.z + fn * v1.z;
    acc[7] = (float)hs[7] + s1.w + fn * v1.w;
    int base = (node - n) * npg;
    for (int k = 0; k < npg; k += 4) {
      bf16x8 hx[4];
      #pragma unroll
      for (int u = 0; u < 4; ++u)
        hx[u] = *(const bf16x8*)(xn + ((size_t)(base + k + u) << 7) + ch0);
      #pragma unroll
      for (int u = 0; u < 4; ++u)
        #pragma unroll
        for (int j = 0; j < 8; ++j) acc[j] += (float)hx[u][j];
    }
  }

  bf16x8 o;
  #pragma unroll
  for (int j = 0; j < 8; ++j) o[j] = (bf16_t)acc[j];
  *(bf16x8*)(agg + ((size_t)node << 7) + ch0) = o;
}

// Fused MLP: y = relu(agg@W1+b1)@W2+b2, FiLM, batchnorm stats.  (r11 measured-best)
// 512 threads / 8 waves; wave owns 32 GEMM1-cols and 16 GEMM2-cols, all 64 rows.
__launch_bounds__(512, 4)
__global__ void k_mlp(const bf16_t* __restrict__ agg, const bf16_t* __restrict__ W1T,
                      const bf16_t* __restrict__ W2T, const float* __restrict__ b1,
                      const float* __restrict__ b2, const float* __restrict__ gamma,
                      const float* __restrict__ beta, const int* __restrict__ batch,
                      bf16_t* __restrict__ y, float* __restrict__ gstats, int n, int N) {
  __shared__ __align__(16) char As[16384];   // [64][128] bf16, swizzled ^((r&7)<<4)
  __shared__ __align__(16) char Hs[32768];   // [64][256] bf16, swizzled ^((r&15)<<4)
  __shared__ float sred[256];
  const int tid = threadIdx.x;
  const int m0 = blockIdx.x * 64;
  const int wave = tid >> 6, lane = tid & 63;
  const int lr = lane & 15, lk = lane >> 4;
  if (tid < 256) sred[tid] = 0.f;

  // stage A tile: 64 rows x 256B = 1024 x 16B chunks, 512 threads x 2
  #pragma unroll
  for (int it = 0; it < 2; ++it) {
    int e = it * 512 + tid;
    int row = e >> 4, c16 = e & 15;
    bf16x8 v = *(const bf16x8*)(agg + ((size_t)(m0 + row) << 7) + c16 * 8);
    int byte = (row << 8) + (c16 << 4);
    byte ^= (row & 7) << 4;
    *(bf16x8*)(As + byte) = v;
  }

  // preload GEMM1 B frags: wave owns cols [32*wave, 32*wave+32)
  const int c1base = wave * 32;
  bf16x8 bb1[2][4];
  #pragma unroll
  for (int cf = 0; cf < 2; ++cf)
    #pragma unroll
    for (int kk = 0; kk < 4; ++kk)
      bb1[cf][kk] = *(const bf16x8*)(W1T + ((c1base + cf * 16 + lr) << 7) + kk * 32 + (lk << 3));

  __syncthreads();

  f32x4 zero4 = {0.f, 0.f, 0.f, 0.f};
  f32x4 acc1[4][2];
  #pragma unroll
  for (int rf = 0; rf < 4; ++rf)
    #pragma unroll
    for (int cf = 0; cf < 2; ++cf) acc1[rf][cf] = zero4;

  #pragma unroll
  for (int kk = 0; kk < 4; ++kk) {
    bf16x8 a[4];
    #pragma unroll
    for (int rf = 0; rf < 4; ++rf) {
      int arow = rf * 16 + lr;
      int abyte = (arow << 8) + kk * 64 + (lk << 4);
      abyte ^= (arow & 7) << 4;
      a[rf] = *(const bf16x8*)(As + abyte);
    }
    #pragma unroll
    for (int rf = 0; rf < 4; ++rf)
      #pragma unroll
      for (int cf = 0; cf < 2; ++cf)
        acc1[rf][cf] = __builtin_amdgcn_mfma_f32_16x16x32_bf16(a[rf], bb1[cf][kk], acc1[rf][cf], 0, 0, 0);
  }

  // epilogue1: bias + relu -> Hs (bf16, swizzled)
  #pragma unroll
  for (int cf = 0; cf < 2; ++cf) {
    int col = c1base + cf * 16 + lr;
    float bias = b1[col];
    #pragma unroll
    for (int rf = 0; rf < 4; ++rf)
      #pragma unroll
      for (int j = 0; j < 4; ++j) {
        int r = rf * 16 + lk * 4 + j;
        float h = acc1[rf][cf][j] + bias;
        h = h > 0.f ? h : 0.f;
        int byte = (r << 9) + col * 2;
        byte ^= (r & 15) << 4;
        *(bf16_t*)(Hs + byte) = (bf16_t)h;
      }
  }

  // preload GEMM2 B frags: wave owns cols [16*wave, 16*wave+16)
  const int c2base = wave * 16;
  bf16x8 bb2[8];
  #pragma unroll
  for (int kk = 0; kk < 8; ++kk)
    bb2[kk] = *(const bf16x8*)(W2T + ((c2base + lr) << 8) + kk * 32 + (lk << 3));

  __syncthreads();

  f32x4 acc2[4];
  #pragma unroll
  for (int rf = 0; rf < 4; ++rf) acc2[rf] = zero4;

  #pragma unroll
  for (int kk = 0; kk < 8; ++kk) {
    bf16x8 a2[4];
    #pragma unroll
    for (int rf = 0; rf < 4; ++rf) {
      int row = rf * 16 + lr;
      int byte = (row << 9) + kk * 64 + (lk << 4);
      byte ^= (row & 15) << 4;
      a2[rf] = *(const bf16x8*)(Hs + byte);
    }
    #pragma unroll
    for (int rf = 0; rf < 4; ++rf)
      acc2[rf] = __builtin_amdgcn_mfma_f32_16x16x32_bf16(a2[rf], bb2[kk], acc2[rf], 0, 0, 0);
  }

  int gb[4][4];
  #pragma unroll
  for (int rf = 0; rf < 4; ++rf)
    #pragma unroll
    for (int j = 0; j < 4; ++j) {
      int row = m0 + rf * 16 + lk * 4 + j;
      gb[rf][j] = (gamma != nullptr && row < n) ? batch[row] : -1;
    }

  {
    int col = c2base + lr;
    float bias = b2[col];
    float s = 0.f, q = 0.f;
    #pragma unroll
    for (int rf = 0; rf < 4; ++rf)
      #pragma unroll
      for (int j = 0; j < 4; ++j) {
        int row = m0 + rf * 16 + lk * 4 + j;
        float v = acc2[rf][j] + bias;
        if (gb[rf][j] >= 0)
          v = gamma[(size_t)gb[rf][j] * 128 + col] * v + beta[(size_t)gb[rf][j] * 128 + col];
        y[(size_t)row * 128 + col] = (bf16_t)v;
        s += v; q += v * v;
      }
    s += __shfl_xor(s, 16, 64); s += __shfl_xor(s, 32, 64);
    q += __shfl_xor(q, 16, 64); q += __shfl_xor(q, 32, 64);
    if (lane < 16) { sred[col] = s; sred[128 + col] = q; }  // cols wave-partitioned
  }
  __syncthreads();
  if (tid < 256) atomicAdd(&gstats[((blockIdx.x & 15) << 8) + tid], sred[tid]);
}

// final normalize (no relu) with in-block finalize; first n rows -> d_out (f32)
__global__ void k_norm(const bf16_t* __restrict__ yin, const float* __restrict__ part,
                       const float* __restrict__ bnw, const float* __restrict__ bnb,
                       float invN, float* __restrict__ out, int total8) {
  __shared__ float ss[256];
  const int tid = threadIdx.x;
  if (tid < 128) {
    float s = 0.f, q = 0.f;
    #pragma unroll
    for (int c = 0; c < 16; ++c) { s += part[c * 256 + tid]; q += part[c * 256 + 128 + tid]; }
    float mean = s * invN;
    float var = fmaxf(q * invN - mean * mean, 0.f);
    float inv = rsqrtf(var + EPSV);
    float sc = inv * bnw[tid];
    ss[tid] = sc;
    ss[128 + tid] = bnb[tid] - mean * sc;
  }
  __syncthreads();
  int i = blockIdx.x * 256 + tid;
  if (i >= total8) return;
  int ch0 = (i & 15) * 8;
  bf16x8 v = ((const bf16x8*)yin)[i];
  float4 r0, r1;
  r0.x = (float)v[0] * ss[ch0 + 0] + ss[128 + ch0 + 0];
  r0.y = (float)v[1] * ss[ch0 + 1] + ss[128 + ch0 + 1];
  r0.z = (float)v[2] * ss[ch0 + 2] + ss[128 + ch0 + 2];
  r0.w = (float)v[3] * ss[ch0 + 3] + ss[128 + ch0 + 3];
  r1.x = (float)v[4] * ss[ch0 + 4] + ss[128 + ch0 + 4];
  r1.y = (float)v[5] * ss[ch0 + 5] + ss[128 + ch0 + 5];
  r1.z = (float)v[6] * ss[ch0 + 6] + ss[128 + ch0 + 6];
  r1.w = (float)v[7] * ss[ch0 + 7] + ss[128 + ch0 + 7];
  ((float4*)out)[i * 2] = r0;
  ((float4*)out)[i * 2 + 1] = r1;
}

extern "C" void kernel_launch(void* const* d_in, const int* in_sizes, int n_in,
                              void* d_out, int out_size, void* d_ws, size_t ws_size,
                              hipStream_t stream) {
  const int*   x_atoms    = (const int*)d_in[0];
  const int*   edge_index = (const int*)d_in[1];
  const int*   edge_attr  = (const int*)d_in[2];
  const int*   batch      = (const int*)d_in[3];
  const float* task_embs  = (const float*)d_in[6];
  const float* teb        = (const float*)d_in[7];
  const float* emb1       = (const float*)d_in[8];
  const float* emb2       = (const float*)d_in[9];
  const float* edge_e1    = (const float*)d_in[10];
  const float* edge_e2    = (const float*)d_in[11];
  const float* W1         = (const float*)d_in[12];
  const float* b1         = (const float*)d_in[13];
  const float* W2         = (const float*)d_in[14];
  const float* b2         = (const float*)d_in[15];
  const float* bnw        = (const float*)d_in[16];
  const float* bnb        = (const float*)d_in[17];
  const float* fWg        = (const float*)d_in[18];
  const float* fbg        = (const float*)d_in[19];
  const float* fWb        = (const float*)d_in[20];
  const float* fbb        = (const float*)d_in[21];

  const int n   = in_sizes[0] / 2;
  const int E   = in_sizes[1] / 2;
  const int g   = in_sizes[6] / 128;
  const int N   = n + g;
  const int npg = n / g;
  const int L   = in_sizes[12] / 32768;

  char* ws = (char*)d_ws;
  size_t off = 0;
  auto alloc = [&](size_t bytes) { size_t o = off; off += (bytes + 255) & ~(size_t)255; return o; };
  bf16_t* xbuf   = (bf16_t*)(ws + alloc((size_t)N * 128 * 2));
  bf16_t* xn     = (bf16_t*)(ws + alloc((size_t)N * 128 * 2));
  bf16_t* aggb   = (bf16_t*)(ws + alloc((size_t)N * 128 * 2));
  float*  gbuf   = (float*)(ws + alloc((size_t)4 * g * 128 * 4));
  bf16_t* W1Tb   = (bf16_t*)(ws + alloc((size_t)L * 32768 * 2));
  bf16_t* W2Tb   = (bf16_t*)(ws + alloc((size_t)L * 32768 * 2));
  bf16_t* fWTb   = (bf16_t*)(ws + alloc((size_t)4 * 16384 * 2));
  bf16_t* tebuf  = (bf16_t*)(ws + alloc((size_t)g * 128 * 2));
  float*  ecomb  = (float*)(ws + alloc((size_t)L * 18 * 128 * 4));
  float*  gstats = (float*)(ws + alloc((size_t)8192 * 4));   // 2 ping-pong zones x 4096
  int*    row_ptr= (int*)(ws + alloc((size_t)(n + 1) * 4));
  int*    fill   = (int*)(ws + alloc((size_t)n * 4));
  int*    epack  = (int*)(ws + alloc((size_t)E * 4));
  int*    bsum   = (int*)(ws + alloc(512 * 4));
  (void)ws_size; (void)n_in; (void)out_size;

  // one-time-per-launch precompute (merged)
  const int prep_total = L * 32768 + 4 * 16384 + g * 128 + L * 18 * 128;
  k_prep_all<<<(prep_total + 255) / 256, 256, 0, stream>>>(W1, W2, W1Tb, W2Tb,
      fWg, fWb, fWTb, task_embs, tebuf, edge_e1, edge_e2, ecomb, L, g);
  k_init_x<<<(N * 128 + 255) / 256, 256, 0, stream>>>(x_atoms, teb, emb1, emb2, xn, n, N);
  k_film<<<(g / 64) * 4, 256, 0, stream>>>(tebuf, fWTb, fbg, fbb, gbuf, g);

  // CSR build (by dst) for real edges
  const int nb = (n + 255) / 256;
  k_zeroi<<<nb, 256, 0, stream>>>(fill, n);
  k_hist<<<(E + 255) / 256, 256, 0, stream>>>(edge_index, fill, E);
  k_scan1<<<nb, 256, 0, stream>>>(fill, row_ptr, bsum, n);
  k_scan2<<<1, 512, 0, stream>>>(bsum, nb);
  k_scan3<<<nb, 256, 0, stream>>>(row_ptr, bsum, fill, n, E);
  k_scatter<<<(E + 255) / 256, 256, 0, stream>>>(edge_index, edge_attr, fill, epack, E);

  k_zerof<<<32, 256, 0, stream>>>(gstats, 8192);   // zero both zones once
  const float invN = 1.0f / (float)N;
  for (int l = 0; l < 4; ++l) {
    float* zone  = gstats + (size_t)(l & 1) * 4096;          // mlp(l) atomics target
    float* zprev = gstats + (size_t)((l - 1) & 1) * 4096;    // stats of layer l-1
    if (l > 0)
      k_normx<<<(N * 16 + 255) / 256, 256, 0, stream>>>(xbuf, zprev, zone,
          bnw + (l - 1) * 128, bnb + (l - 1) * 128, invN, xn, N * 16);
    k_agg<<<(N + 15) / 16, 256, 0, stream>>>(xn, batch, row_ptr, epack,
        ecomb + (size_t)l * 18 * 128, aggb, n, N, npg);
    const float* gm = nullptr; const float* bt = nullptr;
    if (l == 1) { gm = gbuf;                       bt = gbuf + (size_t)g * 128; }
    if (l == 3) { gm = gbuf + (size_t)2 * g * 128; bt = gbuf + (size_t)3 * g * 128; }
    k_mlp<<<(N + 63) / 64, 512, 0, stream>>>(aggb, W1Tb + (size_t)l * 32768,
        W2Tb + (size_t)l * 32768, b1 + l * 256, b2 + l * 128, gm, bt, batch,
        xbuf, zone, n, N);
  }
  // layer 3 stats live in zone 1
  k_norm<<<(n * 16 + 255) / 256, 256, 0, stream>>>(xbuf, gstats + 4096,
      bnw + 3 * 128, bnb + 3 * 128, invN, (float*)d_out, n * 16);
}